// Round 7
// baseline (690.768 us; speedup 1.0000x reference)
//
#include <hip/hip_runtime.h>
#include <hip/hip_cooperative_groups.h>
#include <cstdint>

namespace cg = cooperative_groups;

#define EMB 1024
#define HID 2048
#define BATCH 4
#define SEQ 2048
#define MROWS (BATCH * SEQ) /* 8192 */
#define N1 (3 * HID)        /* 6144 */
#define K1 EMB              /* 1024 */
#define N2 EMB              /* 1024 */
#define K2 HID              /* 2048 */

#define NX (MROWS * EMB)  /* 8388608 */
#define NW1 (N1 * K1)     /* 6291456 */
#define NW2 (N2 * K2)     /* 2097152 */

#define SEG 32            /* global time segments */
#define SLEN (SEQ / SEG)  /* 64 steps per segment */

typedef unsigned short ushort_t;
typedef __bf16 bf16x8 __attribute__((ext_vector_type(8)));
typedef float f32x4 __attribute__((ext_vector_type(4)));
typedef ushort_t us4 __attribute__((ext_vector_type(4)));

__device__ __forceinline__ ushort_t f2bf(float f) {
    uint32_t u = __builtin_bit_cast(uint32_t, f);
    u += 0x7fffu + ((u >> 16) & 1u);  // round-to-nearest-even
    return (ushort_t)(u >> 16);
}
__device__ __forceinline__ float bf2f(ushort_t h) {
    uint32_t u = ((uint32_t)h) << 16;
    return __builtin_bit_cast(float, u);
}
__device__ __forceinline__ float bflo(uint32_t v) {
    return __builtin_bit_cast(float, v << 16);
}
__device__ __forceinline__ float bfhi(uint32_t v) {
    return __builtin_bit_cast(float, v & 0xffff0000u);
}
__device__ __forceinline__ float sigm(float x) {
    return 1.f / (1.f + __expf(-x));
}

// async global->LDS, 16B per lane; LDS dest is wave-uniform base + lane*16
__device__ __forceinline__ void gload_lds16(const ushort_t* g, const ushort_t* l) {
    __builtin_amdgcn_global_load_lds(
        (const __attribute__((address_space(1))) void*)(uintptr_t)(g),
        (__attribute__((address_space(3))) void*)(uint32_t)(uintptr_t)(l),
        16, 0, 0);
}

// ---------------------------------------------------------------------------
// fp32 -> bf16 pre-convert of x, w1, w2
// ---------------------------------------------------------------------------
__global__ __launch_bounds__(256) void cvt_kernel(
    const float* __restrict__ x, const float* __restrict__ w1,
    const float* __restrict__ w2, ushort_t* __restrict__ xb,
    ushort_t* __restrict__ w1b, ushort_t* __restrict__ w2b) {
    const int i = (blockIdx.x * 256 + threadIdx.x) * 4;
    const float* s;
    ushort_t* d;
    if (i < NX) {
        s = x + i; d = xb + i;
    } else if (i < NX + NW1) {
        s = w1 + (i - NX); d = w1b + (i - NX);
    } else {
        s = w2 + (i - NX - NW1); d = w2b + (i - NX - NW1);
    }
    const float4 v = *(const float4*)s;
    us4 o;
    o.x = f2bf(v.x); o.y = f2bf(v.y); o.z = f2bf(v.z); o.w = f2bf(v.w);
    *(us4*)d = o;
}

// ---------------------------------------------------------------------------
// C[M,N] = A[M,K] * B[N,K]^T   (bf16 in, fp32 acc, bf16 or fp32 out)
// 128x128 tile, BK=32, 4 waves, each wave 64x64 via 4x4 mfma_f32_16x16x32_bf16
// Bank-conflict-free swizzle (verified R2: 1.26e7 -> 0). Unsplit (R6's split
// cost 18 us via duplicated A fetch: 71.7x2 vs 90 MB).
// ---------------------------------------------------------------------------
template <bool OUT_BF16>
__global__ __launch_bounds__(256) void gemm_bt(
    const ushort_t* __restrict__ A, const ushort_t* __restrict__ B,
    void* __restrict__ Cv, int M, int N, int K) {
    __shared__ ushort_t sA[128 * 32];  // [m][kslot] row-major, 64B rows
    __shared__ ushort_t sB[128 * 32];  // [n][kslot] row-major

    const int tid  = threadIdx.x;
    const int lane = tid & 63;
    const int wave = tid >> 6;
    const int quad = lane >> 4;
    const int l16  = lane & 15;
    const long tm0 = (long)blockIdx.y * 128;
    const long tn0 = (long)blockIdx.x * 128;
    const int wm = (wave & 1) * 64;
    const int wn = (wave >> 1) * 64;

    f32x4 acc[4][4] = {};

    const int ar0 = tid >> 2;
    const int ar1 = (tid + 256) >> 2;
    const int kq  = (tid & 3) ^ ((ar0 >> 1) & 3);
    const int ac  = kq * 8;
    const ushort_t* gA = A + (size_t)tm0 * K;
    const ushort_t* gB = B + (size_t)tn0 * K;
    ushort_t* lb0 = &sA[0] + wave * 512;
    ushort_t* lb1 = &sA[0] + 2048 + wave * 512;
    ushort_t* lb2 = &sB[0] + wave * 512;
    ushort_t* lb3 = &sB[0] + 2048 + wave * 512;

    const int rsw = (l16 >> 1) & 3;
    const int aoff = (quad ^ rsw) * 8 + l16 * 32;

    for (int k0 = 0; k0 < K; k0 += 32) {
        __syncthreads();
        gload_lds16(gA + (size_t)ar0 * K + k0 + ac, lb0);
        gload_lds16(gA + (size_t)ar1 * K + k0 + ac, lb1);
        gload_lds16(gB + (size_t)ar0 * K + k0 + ac, lb2);
        gload_lds16(gB + (size_t)ar1 * K + k0 + ac, lb3);
        __syncthreads();

        bf16x8 af[4], bfr[4];
#pragma unroll
        for (int i = 0; i < 4; ++i)
            af[i] = *(const bf16x8*)&sA[(wm + i * 16) * 32 + aoff];
#pragma unroll
        for (int j = 0; j < 4; ++j)
            bfr[j] = *(const bf16x8*)&sB[(wn + j * 16) * 32 + aoff];
#pragma unroll
        for (int i = 0; i < 4; ++i)
#pragma unroll
            for (int j = 0; j < 4; ++j)
                acc[i][j] = __builtin_amdgcn_mfma_f32_16x16x32_bf16(
                    af[i], bfr[j], acc[i][j], 0, 0, 0);
    }

    // epilogue: C/D layout col=lane&15, row=quad*4+reg
#pragma unroll
    for (int i = 0; i < 4; ++i) {
        const long row0 = tm0 + wm + i * 16 + quad * 4;
#pragma unroll
        for (int j = 0; j < 4; ++j) {
            const long col = tn0 + wn + j * 16 + l16;
#pragma unroll
            for (int r = 0; r < 4; ++r) {
                if constexpr (OUT_BF16) {
                    ((ushort_t*)Cv)[(size_t)(row0 + r) * N + col] = f2bf(acc[i][j][r]);
                } else {
                    ((float*)Cv)[(size_t)(row0 + r) * N + col] = acc[i][j][r];
                }
            }
        }
    }
}

// ---------------------------------------------------------------------------
// Cooperative single-kernel scan. Same math/data path as R3/R6 (absmax-
// identical), but z,h stay in REGISTERS across grid.sync(), eliminating the
// 64 MB z/h re-read and two kernel launches.
//   gid = blk*256+tid; ch=(gid&1023)*2; bs=gid>>10; b=bs>>5; seg=bs&31
//   (each block has one (b,seg); covers 512 adjacent channels)
// Phase 1: load z,h (64 x uint32 regs each), per-segment aggregate -> Ag/Bg.
// grid.sync(). Phase 2: each thread redundantly combines Ag/Bg[s<seg] from
// L2 (<=127 KB/block) -> carry. Phase 3: replay from registers, write u.
// 512 blocks x 256 thr; ~160 VGPR -> >=2 blocks/CU -> co-resident (runtime
// validates; no R5-style register cap).
// ---------------------------------------------------------------------------
__global__ void scan_coop(
    const ushort_t* __restrict__ y, const float* __restrict__ cw,
    float* __restrict__ Ag, float* __restrict__ Bg,
    ushort_t* __restrict__ u) {
    const int gid = blockIdx.x * 256 + threadIdx.x;
    const int ch  = (gid & 1023) * 2;
    const int bs  = gid >> 10;
    const int b   = bs >> 5;
    const int seg = bs & 31;
    const int t0  = seg * SLEN;
    const size_t rowbase = (size_t)b * SEQ;
    const ushort_t* yo = y + ch;
    const ushort_t* yz = y + 2048 + ch;
    const ushort_t* yh = y + 4096 + ch;

    float w[2][4];
#pragma unroll
    for (int c = 0; c < 2; ++c)
#pragma unroll
        for (int k = 0; k < 4; ++k) w[c][k] = cw[(ch + c) * 4 + k];

    auto ld2 = [&](const ushort_t* p, int t) -> uint32_t {
        return *(const uint32_t*)(p + (rowbase + (size_t)t) * 6144);
    };
    auto zpair = [&](int t, float* out) {
        if (t < 0) { out[0] = 0.f; out[1] = 0.f; }
        else { uint32_t v = ld2(yz, t); out[0] = bflo(v); out[1] = bfhi(v); }
    };

    // bulk-load z,h into registers (persist across grid.sync)
    uint32_t za[SLEN], ha[SLEN];
#pragma unroll
    for (int t = 0; t < SLEN; ++t) {
        za[t] = ld2(yz, t0 + t);
        ha[t] = ld2(yh, t0 + t);
    }
    float zw1[2], zw2[2], zw3[2];  // conv warm-up (t0-1, t0-2, t0-3)
    zpair(t0 - 1, zw1); zpair(t0 - 2, zw2); zpair(t0 - 3, zw3);

    // phase 1: per-segment aggregate
    float z1[2] = {zw1[0], zw1[1]}, z2[2] = {zw2[0], zw2[1]}, z3[2] = {zw3[0], zw3[1]};
    float A[2] = {1.f, 1.f}, Bv[2] = {0.f, 0.f};
#pragma unroll
    for (int t = 0; t < SLEN; ++t) {
        const float zr[2] = {bflo(za[t]), bfhi(za[t])};
        const float hr[2] = {bflo(ha[t]), bfhi(ha[t])};
#pragma unroll
        for (int c = 0; c < 2; ++c) {
            const float cv = w[c][0] * z3[c] + w[c][1] * z2[c] +
                             w[c][2] * z1[c] + w[c][3] * zr[c];
            const float s = sigm(cv);
            z3[c] = z2[c]; z2[c] = z1[c]; z1[c] = zr[c];
            const float a = 1.f - s;
            A[c] *= a;
            Bv[c] = a * Bv[c] + s * hr[c];
        }
    }
    const size_t aidx = ((size_t)b * SEG + seg) * HID + ch;
    *(float2*)&Ag[aidx] = make_float2(A[0], A[1]);
    *(float2*)&Bg[aidx] = make_float2(Bv[0], Bv[1]);

    cg::this_grid().sync();

    // phase 2: redundant look-back over earlier segments (L2-resident, 2 MB)
    float h[2] = {0.f, 0.f};
    for (int s = 0; s < seg; ++s) {
        const size_t idx = ((size_t)b * SEG + s) * HID + ch;
        const float2 a2 = *(const float2*)&Ag[idx];
        const float2 b2 = *(const float2*)&Bg[idx];
        h[0] = a2.x * h[0] + b2.x;
        h[1] = a2.y * h[1] + b2.y;
    }

    // phase 3: replay from registers with carry, write silu(o1)*h
    z1[0] = zw1[0]; z1[1] = zw1[1];
    z2[0] = zw2[0]; z2[1] = zw2[1];
    z3[0] = zw3[0]; z3[1] = zw3[1];
#pragma unroll
    for (int t = 0; t < SLEN; ++t) {
        const uint32_t vo = ld2(yo, t0 + t);
        const float zr[2] = {bflo(za[t]), bfhi(za[t])};
        const float hr[2] = {bflo(ha[t]), bfhi(ha[t])};
        const float o1[2] = {bflo(vo), bfhi(vo)};
        ushort_t res[2];
#pragma unroll
        for (int c = 0; c < 2; ++c) {
            const float cv = w[c][0] * z3[c] + w[c][1] * z2[c] +
                             w[c][2] * z1[c] + w[c][3] * zr[c];
            const float s = sigm(cv);
            z3[c] = z2[c]; z2[c] = z1[c]; z1[c] = zr[c];
            h[c] = (1.f - s) * h[c] + s * hr[c];
            const float sil = o1[c] * sigm(o1[c]);
            res[c] = f2bf(sil * h[c]);
        }
        *(uint32_t*)&u[(rowbase + (size_t)(t0 + t)) * (size_t)HID + ch] =
            (uint32_t)res[0] | ((uint32_t)res[1] << 16);
    }
}

// ---------------------------------------------------------------------------
extern "C" void kernel_launch(void* const* d_in, const int* in_sizes, int n_in,
                              void* d_out, int out_size, void* d_ws, size_t ws_size,
                              hipStream_t stream) {
    const float* x  = (const float*)d_in[0];
    const float* w1 = (const float*)d_in[1];
    const float* w2 = (const float*)d_in[2];
    const float* cw = (const float*)d_in[3];
    char* ws = (char*)d_ws;

    // ws layout (bytes): xb 16MiB | w1b 12MiB | w2b 4MiB | y 96MiB | u 32MiB = 160MiB
    ushort_t* xb  = (ushort_t*)(ws);
    ushort_t* w1b = (ushort_t*)(ws + (size_t)16777216);
    ushort_t* w2b = (ushort_t*)(ws + (size_t)29360128);
    ushort_t* y   = (ushort_t*)(ws + (size_t)33554432);
    ushort_t* u   = (ushort_t*)(ws + (size_t)134217728);
    // scan scratch reuses the xb region (dead after GEMM1): 2 x 1 MiB fp32
    float* Ag = (float*)(ws);
    float* Bg = (float*)(ws + (size_t)1048576);
    float* out = (float*)d_out;

    cvt_kernel<<<16384, 256, 0, stream>>>(x, w1, w2, xb, w1b, w2b);
    gemm_bt<true><<<dim3(N1 / 128, MROWS / 128), 256, 0, stream>>>(
        xb, w1b, (void*)y, MROWS, N1, K1);
    {
        const ushort_t* ya = y;
        const float* cwa = cw;
        float* Aga = Ag;
        float* Bga = Bg;
        ushort_t* ua = u;
        void* args[] = {(void*)&ya, (void*)&cwa, (void*)&Aga, (void*)&Bga, (void*)&ua};
        hipLaunchCooperativeKernel((void*)scan_coop, dim3(512), dim3(256),
                                   args, 0, stream);
    }
    gemm_bt<false><<<dim3(N2 / 128, MROWS / 128), 256, 0, stream>>>(
        u, w2b, (void*)out, MROWS, N2, K2);
}

// Round 8
// 337.908 us; speedup vs baseline: 2.0443x; 2.0443x over previous
//
#include <hip/hip_runtime.h>
#include <cstdint>

#define EMB 1024
#define HID 2048
#define BATCH 4
#define SEQ 2048
#define MROWS (BATCH * SEQ) /* 8192 */
#define N1 (3 * HID)        /* 6144 */
#define K1 EMB              /* 1024 */
#define N2 EMB              /* 1024 */
#define K2 HID              /* 2048 */

#define NX (MROWS * EMB)  /* 8388608 */
#define NW1 (N1 * K1)     /* 6291456 */
#define NW2 (N2 * K2)     /* 2097152 */

#define SEG 32            /* global time segments */
#define SLEN (SEQ / SEG)  /* 64 steps per segment */

typedef unsigned short ushort_t;
typedef __bf16 bf16x8 __attribute__((ext_vector_type(8)));
typedef float f32x4 __attribute__((ext_vector_type(4)));
typedef ushort_t us4 __attribute__((ext_vector_type(4)));

__device__ __forceinline__ ushort_t f2bf(float f) {
    uint32_t u = __builtin_bit_cast(uint32_t, f);
    u += 0x7fffu + ((u >> 16) & 1u);  // round-to-nearest-even
    return (ushort_t)(u >> 16);
}
__device__ __forceinline__ float bf2f(ushort_t h) {
    uint32_t u = ((uint32_t)h) << 16;
    return __builtin_bit_cast(float, u);
}
__device__ __forceinline__ float bflo(uint32_t v) {
    return __builtin_bit_cast(float, v << 16);
}
__device__ __forceinline__ float bfhi(uint32_t v) {
    return __builtin_bit_cast(float, v & 0xffff0000u);
}
__device__ __forceinline__ float sigm(float x) {
    return 1.f / (1.f + __expf(-x));
}

// async global->LDS, 16B per lane; LDS dest is wave-uniform base + lane*16
__device__ __forceinline__ void gload_lds16(const ushort_t* g, const ushort_t* l) {
    __builtin_amdgcn_global_load_lds(
        (const __attribute__((address_space(1))) void*)(uintptr_t)(g),
        (__attribute__((address_space(3))) void*)(uint32_t)(uintptr_t)(l),
        16, 0, 0);
}

// ---------------------------------------------------------------------------
// fp32 -> bf16 pre-convert of x, w1, w2
// ---------------------------------------------------------------------------
__global__ __launch_bounds__(256) void cvt_kernel(
    const float* __restrict__ x, const float* __restrict__ w1,
    const float* __restrict__ w2, ushort_t* __restrict__ xb,
    ushort_t* __restrict__ w1b, ushort_t* __restrict__ w2b) {
    const int i = (blockIdx.x * 256 + threadIdx.x) * 4;
    const float* s;
    ushort_t* d;
    if (i < NX) {
        s = x + i; d = xb + i;
    } else if (i < NX + NW1) {
        s = w1 + (i - NX); d = w1b + (i - NX);
    } else {
        s = w2 + (i - NX - NW1); d = w2b + (i - NX - NW1);
    }
    const float4 v = *(const float4*)s;
    us4 o;
    o.x = f2bf(v.x); o.y = f2bf(v.y); o.z = f2bf(v.z); o.w = f2bf(v.w);
    *(us4*)d = o;
}

// ---------------------------------------------------------------------------
// C[M,N] = A[M,K] * B[N,K]^T   (bf16 in, fp32 acc, bf16 or fp32 out)
// 128x128 tile; BK=64 staged as TWO independent 32-k panels per barrier pair
// (halves the vmcnt(0)+s_barrier drain events — the m97-plateau stall).
// Each panel keeps the R2-verified 64-B-row layout + XOR swizzle
// (SQ_LDS_BANK_CONFLICT == 0). LDS 32 KB/block.
// ---------------------------------------------------------------------------
template <bool OUT_BF16>
__global__ __launch_bounds__(256) void gemm_bt(
    const ushort_t* __restrict__ A, const ushort_t* __restrict__ B,
    void* __restrict__ Cv, int M, int N, int K) {
    __shared__ ushort_t sA[2 * 128 * 32];  // two [m][kslot] panels, 64B rows
    __shared__ ushort_t sB[2 * 128 * 32];

    const int tid  = threadIdx.x;
    const int lane = tid & 63;
    const int wave = tid >> 6;
    const int quad = lane >> 4;
    const int l16  = lane & 15;
    const long tm0 = (long)blockIdx.y * 128;
    const long tn0 = (long)blockIdx.x * 128;
    const int wm = (wave & 1) * 64;
    const int wn = (wave >> 1) * 64;

    f32x4 acc[4][4] = {};

    const int ar0 = tid >> 2;
    const int ar1 = (tid + 256) >> 2;
    const int kq  = (tid & 3) ^ ((ar0 >> 1) & 3);
    const int ac  = kq * 8;
    const ushort_t* gA = A + (size_t)tm0 * K;
    const ushort_t* gB = B + (size_t)tn0 * K;

    const int rsw = (l16 >> 1) & 3;
    const int aoff = (quad ^ rsw) * 8 + l16 * 32;

    for (int k0 = 0; k0 < K; k0 += 64) {
        __syncthreads();
#pragma unroll
        for (int p = 0; p < 2; ++p) {
            const int kp = k0 + p * 32;
            ushort_t* pA = &sA[p * 4096];
            ushort_t* pB = &sB[p * 4096];
            gload_lds16(gA + (size_t)ar0 * K + kp + ac, pA + wave * 512);
            gload_lds16(gA + (size_t)ar1 * K + kp + ac, pA + 2048 + wave * 512);
            gload_lds16(gB + (size_t)ar0 * K + kp + ac, pB + wave * 512);
            gload_lds16(gB + (size_t)ar1 * K + kp + ac, pB + 2048 + wave * 512);
        }
        __syncthreads();

#pragma unroll
        for (int p = 0; p < 2; ++p) {
            const ushort_t* pA = &sA[p * 4096];
            const ushort_t* pB = &sB[p * 4096];
            bf16x8 af[4], bfr[4];
#pragma unroll
            for (int i = 0; i < 4; ++i)
                af[i] = *(const bf16x8*)&pA[(wm + i * 16) * 32 + aoff];
#pragma unroll
            for (int j = 0; j < 4; ++j)
                bfr[j] = *(const bf16x8*)&pB[(wn + j * 16) * 32 + aoff];
#pragma unroll
            for (int i = 0; i < 4; ++i)
#pragma unroll
                for (int j = 0; j < 4; ++j)
                    acc[i][j] = __builtin_amdgcn_mfma_f32_16x16x32_bf16(
                        af[i], bfr[j], acc[i][j], 0, 0, 0);
        }
    }

    // epilogue: C/D layout col=lane&15, row=quad*4+reg
#pragma unroll
    for (int i = 0; i < 4; ++i) {
        const long row0 = tm0 + wm + i * 16 + quad * 4;
#pragma unroll
        for (int j = 0; j < 4; ++j) {
            const long col = tn0 + wn + j * 16 + l16;
#pragma unroll
            for (int r = 0; r < 4; ++r) {
                if constexpr (OUT_BF16) {
                    ((ushort_t*)Cv)[(size_t)(row0 + r) * N + col] = f2bf(acc[i][j][r]);
                } else {
                    ((float*)Cv)[(size_t)(row0 + r) * N + col] = acc[i][j][r];
                }
            }
        }
    }
}

// ---------------------------------------------------------------------------
// Segmented scan, 3 kernels (R3 structure, validated). Thread owns 2 adjacent
// channels (ushort2 loads: 32 lanes x 4 B = full 128-B lines).
// NOTE (R5/R7): do NOT hold the streams in large register arrays across
// phases — the compiler demotes >~32-dword locals to scratch (VGPR=64 +
// 450 MB spill traffic, twice observed). Re-reading via L3 is faster.
// ---------------------------------------------------------------------------
__global__ __launch_bounds__(256) void scan_part1(
    const ushort_t* __restrict__ y, const float* __restrict__ cw,
    float* __restrict__ Ag, float* __restrict__ Bg) {
    const int gid = blockIdx.x * 256 + threadIdx.x;
    const int ch  = (gid & 1023) * 2;
    const int bs  = gid >> 10;
    const int b   = bs >> 5;
    const int seg = bs & 31;
    const int t0  = seg * SLEN;
    const size_t rowbase = (size_t)b * SEQ;
    const ushort_t* yz = y + 2048 + ch;
    const ushort_t* yh = y + 4096 + ch;

    float w[2][4];
#pragma unroll
    for (int c = 0; c < 2; ++c)
#pragma unroll
        for (int k = 0; k < 4; ++k) w[c][k] = cw[(ch + c) * 4 + k];

    auto ld2 = [&](const ushort_t* p, int t) -> uint32_t {
        return *(const uint32_t*)(p + (rowbase + (size_t)t) * 6144);
    };
    auto zpair = [&](int t, float* out) {
        if (t < 0) { out[0] = 0.f; out[1] = 0.f; }
        else { uint32_t v = ld2(yz, t); out[0] = bflo(v); out[1] = bfhi(v); }
    };

    float z1[2], z2[2], z3[2], A[2] = {1.f, 1.f}, Bv[2] = {0.f, 0.f};
    zpair(t0 - 1, z1); zpair(t0 - 2, z2); zpair(t0 - 3, z3);

#pragma unroll 4
    for (int t = t0; t < t0 + SLEN; ++t) {
        const uint32_t vz = ld2(yz, t);
        const uint32_t vh = ld2(yh, t);
        const float zr[2] = {bflo(vz), bfhi(vz)};
        const float hr[2] = {bflo(vh), bfhi(vh)};
#pragma unroll
        for (int c = 0; c < 2; ++c) {
            const float cv = w[c][0] * z3[c] + w[c][1] * z2[c] +
                             w[c][2] * z1[c] + w[c][3] * zr[c];
            const float s = sigm(cv);
            z3[c] = z2[c]; z2[c] = z1[c]; z1[c] = zr[c];
            const float a = 1.f - s;
            A[c] *= a;
            Bv[c] = a * Bv[c] + s * hr[c];
        }
    }
    const size_t idx = ((size_t)b * SEG + seg) * HID + ch;
    *(float2*)&Ag[idx] = make_float2(A[0], A[1]);
    *(float2*)&Bg[idx] = make_float2(Bv[0], Bv[1]);
}

// one thread per (b, ch): serial exclusive combine over SEG segments
__global__ __launch_bounds__(256) void scan_part2(
    const float* __restrict__ Ag, const float* __restrict__ Bg,
    float* __restrict__ Cr) {
    const int gid = blockIdx.x * 256 + threadIdx.x;  // [0, 8192)
    const int b  = gid >> 11;
    const int ch = gid & 2047;
    float carry = 0.f;
#pragma unroll
    for (int s = 0; s < SEG; ++s) {
        const size_t idx = ((size_t)b * SEG + s) * HID + ch;
        Cr[idx] = carry;
        carry = Ag[idx] * carry + Bg[idx];
    }
}

__global__ __launch_bounds__(256) void scan_part3(
    const ushort_t* __restrict__ y, const float* __restrict__ cw,
    const float* __restrict__ Cr, ushort_t* __restrict__ u) {
    const int gid = blockIdx.x * 256 + threadIdx.x;
    const int ch  = (gid & 1023) * 2;
    const int bs  = gid >> 10;
    const int b   = bs >> 5;
    const int seg = bs & 31;
    const int t0  = seg * SLEN;
    const size_t rowbase = (size_t)b * SEQ;
    const ushort_t* yo = y + ch;
    const ushort_t* yz = y + 2048 + ch;
    const ushort_t* yh = y + 4096 + ch;

    float w[2][4];
#pragma unroll
    for (int c = 0; c < 2; ++c)
#pragma unroll
        for (int k = 0; k < 4; ++k) w[c][k] = cw[(ch + c) * 4 + k];

    auto ld2 = [&](const ushort_t* p, int t) -> uint32_t {
        return *(const uint32_t*)(p + (rowbase + (size_t)t) * 6144);
    };
    auto zpair = [&](int t, float* out) {
        if (t < 0) { out[0] = 0.f; out[1] = 0.f; }
        else { uint32_t v = ld2(yz, t); out[0] = bflo(v); out[1] = bfhi(v); }
    };

    const size_t cidx = ((size_t)b * SEG + seg) * HID + ch;
    float h[2] = {Cr[cidx], Cr[cidx + 1]};
    float z1[2], z2[2], z3[2];
    zpair(t0 - 1, z1); zpair(t0 - 2, z2); zpair(t0 - 3, z3);

#pragma unroll 4
    for (int t = t0; t < t0 + SLEN; ++t) {
        const uint32_t vz = ld2(yz, t);
        const uint32_t vh = ld2(yh, t);
        const uint32_t vo = ld2(yo, t);
        const float zr[2] = {bflo(vz), bfhi(vz)};
        const float hr[2] = {bflo(vh), bfhi(vh)};
        const float o1[2] = {bflo(vo), bfhi(vo)};
        ushort_t res[2];
#pragma unroll
        for (int c = 0; c < 2; ++c) {
            const float cv = w[c][0] * z3[c] + w[c][1] * z2[c] +
                             w[c][2] * z1[c] + w[c][3] * zr[c];
            const float s = sigm(cv);
            z3[c] = z2[c]; z2[c] = z1[c]; z1[c] = zr[c];
            h[c] = (1.f - s) * h[c] + s * hr[c];
            const float sil = o1[c] * sigm(o1[c]);
            res[c] = f2bf(sil * h[c]);
        }
        *(uint32_t*)&u[(rowbase + (size_t)t) * (size_t)HID + ch] =
            (uint32_t)res[0] | ((uint32_t)res[1] << 16);
    }
}

// ---------------------------------------------------------------------------
extern "C" void kernel_launch(void* const* d_in, const int* in_sizes, int n_in,
                              void* d_out, int out_size, void* d_ws, size_t ws_size,
                              hipStream_t stream) {
    const float* x  = (const float*)d_in[0];
    const float* w1 = (const float*)d_in[1];
    const float* w2 = (const float*)d_in[2];
    const float* cw = (const float*)d_in[3];
    char* ws = (char*)d_ws;

    // ws layout (bytes): xb 16MiB | w1b 12MiB | w2b 4MiB | y 96MiB | u 32MiB = 160MiB
    ushort_t* xb  = (ushort_t*)(ws);
    ushort_t* w1b = (ushort_t*)(ws + (size_t)16777216);
    ushort_t* w2b = (ushort_t*)(ws + (size_t)29360128);
    ushort_t* y   = (ushort_t*)(ws + (size_t)33554432);
    ushort_t* u   = (ushort_t*)(ws + (size_t)134217728);
    // scan scratch reuses the xb region (dead after GEMM1): 3 x 1 MiB fp32
    float* Ag = (float*)(ws);
    float* Bg = (float*)(ws + (size_t)1048576);
    float* Cr = (float*)(ws + (size_t)2097152);
    float* out = (float*)d_out;

    cvt_kernel<<<16384, 256, 0, stream>>>(x, w1, w2, xb, w1b, w2b);
    gemm_bt<true><<<dim3(N1 / 128, MROWS / 128), 256, 0, stream>>>(
        xb, w1b, (void*)y, MROWS, N1, K1);
    scan_part1<<<512, 256, 0, stream>>>(y, cw, Ag, Bg);
    scan_part2<<<32, 256, 0, stream>>>(Ag, Bg, Cr);
    scan_part3<<<512, 256, 0, stream>>>(y, cw, Cr, u);
    gemm_bt<false><<<dim3(N2 / 128, MROWS / 128), 256, 0, stream>>>(
        u, w2b, (void*)out, MROWS, N2, K2);
}